// Round 4
// baseline (683.002 us; speedup 1.0000x reference)
//
#include <hip/hip_runtime.h>
#include <math.h>

#define N_TOK 32768
#define DIM   512
#define NEXP  64
#define HID   1024
#define CAP   512

typedef float  f32x4  __attribute__((ext_vector_type(4)));
typedef short  bf16x8 __attribute__((ext_vector_type(8)));

#define GET4(v, jj) ((jj) == 0 ? (v).x : (jj) == 1 ? (v).y : (jj) == 2 ? (v).z : (v).w)

__device__ __forceinline__ unsigned short f2bf(float f) {
  unsigned u = __float_as_uint(f);
  u += 0x7FFFu + ((u >> 16) & 1u);   // RNE
  return (unsigned short)(u >> 16);
}
__device__ __forceinline__ unsigned enc_f(float f) {  // monotone f32 -> u32
  unsigned u = __float_as_uint(f);
  return (u & 0x80000000u) ? ~u : (u | 0x80000000u);
}
__device__ __forceinline__ float dec_f(unsigned k) {
  unsigned u = (k & 0x80000000u) ? (k & 0x7FFFFFFFu) : ~k;
  return __uint_as_float(u);
}

// ---------------- router: logitsT[e][n] = sum_d x[n][d]*rw[d][e], fp64 accum ----------------
__global__ __launch_bounds__(256)
void router_kernel(const float* __restrict__ x, const float* __restrict__ rw,
                   float* __restrict__ logitsT) {
  const int t = threadIdx.x;
  const int n0 = blockIdx.x * 64 + (t >> 4) * 4;   // this thread's 4 tokens
  const int e0 = (t & 15) * 4;                     // this thread's 4 experts
  double acc[16];
#pragma unroll
  for (int i = 0; i < 16; ++i) acc[i] = 0.0;
  for (int k0 = 0; k0 < DIM; k0 += 4) {
    float4 a0 = *(const float4*)(x + (size_t)(n0 + 0) * DIM + k0);
    float4 a1 = *(const float4*)(x + (size_t)(n0 + 1) * DIM + k0);
    float4 a2 = *(const float4*)(x + (size_t)(n0 + 2) * DIM + k0);
    float4 a3 = *(const float4*)(x + (size_t)(n0 + 3) * DIM + k0);
#pragma unroll
    for (int kk = 0; kk < 4; ++kk) {
      float4 b = *(const float4*)(rw + (size_t)(k0 + kk) * NEXP + e0);
      double b0 = (double)b.x, b1 = (double)b.y, b2 = (double)b.z, b3 = (double)b.w;
      double d0 = (double)GET4(a0, kk);
      double d1 = (double)GET4(a1, kk);
      double d2 = (double)GET4(a2, kk);
      double d3 = (double)GET4(a3, kk);
      acc[0]  += d0 * b0; acc[1]  += d0 * b1; acc[2]  += d0 * b2; acc[3]  += d0 * b3;
      acc[4]  += d1 * b0; acc[5]  += d1 * b1; acc[6]  += d1 * b2; acc[7]  += d1 * b3;
      acc[8]  += d2 * b0; acc[9]  += d2 * b1; acc[10] += d2 * b2; acc[11] += d2 * b3;
      acc[12] += d3 * b0; acc[13] += d3 * b1; acc[14] += d3 * b2; acc[15] += d3 * b3;
    }
  }
#pragma unroll
  for (int j = 0; j < 4; ++j)
#pragma unroll
    for (int ee = 0; ee < 4; ++ee)
      logitsT[(size_t)(e0 + ee) * N_TOK + (n0 + j)] = (float)acc[j * 4 + ee];
}

// ------------- per-expert max/sumexp + exact radix top-512 (all loops bounded) -------------
__global__ __launch_bounds__(1024)
void topk_kernel(const float* __restrict__ logitsT, int* __restrict__ tok_idx,
                 float* __restrict__ expw, float* __restrict__ auxout) {
  const int e = blockIdx.x;
  const int t = threadIdx.x;
  const float* row = logitsT + (size_t)e * N_TOK;

  unsigned key[32];          // token n = j*1024 + t
#pragma unroll
  for (int j = 0; j < 32; ++j) key[j] = enc_f(row[j * 1024 + t]);

  __shared__ unsigned ured[1024];
  __shared__ float    fred[1024];
  __shared__ unsigned hist[256];
  __shared__ unsigned sh_chosen, sh_rem, sh_x, sh_pos;

  // block max (deterministic tree)
  unsigned km = 0;
#pragma unroll
  for (int j = 0; j < 32; ++j) km = key[j] > km ? key[j] : km;
  ured[t] = km;
  __syncthreads();
  for (int s = 512; s > 0; s >>= 1) {
    if (t < s) { unsigned o = ured[t + s]; if (o > ured[t]) ured[t] = o; }
    __syncthreads();
  }
  const float m = dec_f(ured[0]);

  float ssum = 0.f;
#pragma unroll
  for (int j = 0; j < 32; ++j) ssum += expf(dec_f(key[j]) - m);
  fred[t] = ssum;
  __syncthreads();
  for (int s = 512; s > 0; s >>= 1) {
    if (t < s) fred[t] += fred[t + s];
    __syncthreads();
  }
  const float invZ = 1.0f / fred[0];

  // radix select (4 passes of 8 bits): exact key of the 512th-largest logit
  if (t == 0) sh_rem = CAP;
  __syncthreads();
  unsigned live = 0xFFFFFFFFu;
  unsigned prefix = 0;
  for (int pass = 0; pass < 4; ++pass) {
    const int shift = 24 - pass * 8;
    if (t < 256) hist[t] = 0;
    __syncthreads();
#pragma unroll
    for (int j = 0; j < 32; ++j)
      if (live & (1u << j)) atomicAdd(&hist[(key[j] >> shift) & 0xFFu], 1u);
    __syncthreads();
    if (t == 0) {
      unsigned need = sh_rem, accum = 0;
      int found = 0;
      for (int b = 255; b >= 0; --b) {
        unsigned cn = hist[b];
        if (!found) {
          if (accum + cn >= need) { sh_chosen = (unsigned)b; sh_rem = need - accum; found = 1; }
          else accum += cn;
        }
      }
    }
    __syncthreads();
    const unsigned ch = sh_chosen;
#pragma unroll
    for (int j = 0; j < 32; ++j)
      if (((key[j] >> shift) & 0xFFu) != ch) live &= ~(1u << j);
    prefix = (prefix << 8) | ch;
    __syncthreads();
  }
  const unsigned ustar = prefix;   // `live` now marks keys == ustar

  // emit all strictly-greater keys
  if (t == 0) sh_pos = 0;
  __syncthreads();
#pragma unroll
  for (int j = 0; j < 32; ++j) {
    if (key[j] > ustar) {
      unsigned p = atomicAdd(&sh_pos, 1u);
      tok_idx[e * CAP + p] = j * 1024 + t;
      expw[e * CAP + p] = expf(dec_f(key[j]) - m) * invZ;
    }
  }
  __syncthreads();
  const unsigned padv = CAP - sh_pos;  // #ties to take, smallest token index first

  // two bounded radix passes over token indices among ties: padv-th smallest index X
  if (t < 256) hist[t] = 0;
  __syncthreads();
#pragma unroll
  for (int j = 0; j < 32; ++j)
    if (live & (1u << j)) atomicAdd(&hist[(j * 1024 + t) >> 7], 1u);
  __syncthreads();
  if (t == 0) {
    unsigned accum = 0;
    int found = 0;
    for (int b = 0; b < 256; ++b) {
      unsigned cn = hist[b];
      if (!found) {
        if (accum + cn >= padv) { sh_chosen = (unsigned)b; sh_rem = padv - accum; found = 1; }
        else accum += cn;
      }
    }
  }
  __syncthreads();
  const unsigned hb = sh_chosen, rem = sh_rem;
  if (t < 256) hist[t] = 0;
  __syncthreads();
#pragma unroll
  for (int j = 0; j < 32; ++j)
    if (live & (1u << j)) {
      int n = j * 1024 + t;
      if ((unsigned)(n >> 7) == hb) atomicAdd(&hist[n & 127], 1u);
    }
  __syncthreads();
  if (t == 0) {
    unsigned accum = 0;
    int found = 0;
    for (int b = 0; b < 128; ++b) {
      unsigned cn = hist[b];
      if (!found) {
        if (accum + cn >= rem) { sh_x = (hb << 7) | (unsigned)b; found = 1; }
        else accum += cn;
      }
    }
  }
  __syncthreads();
  const int X = (int)sh_x;                   // padv-th smallest tie index
#pragma unroll
  for (int j = 0; j < 32; ++j)
    if (live & (1u << j)) {
      int n = j * 1024 + t;
      if (n <= X) {
        unsigned p = atomicAdd(&sh_pos, 1u);
        tok_idx[e * CAP + p] = n;
        expw[e * CAP + p] = expf(dec_f(key[j]) - m) * invZ;
      }
    }
  if (e == 0 && t == 0) { auxout[0] = 2.44140625e-4f; auxout[1] = 0.015625f; }
}

// ---------------- FFN GEMMs: 128x128 tile, BK=64, bf16 MFMA 16x16x32 ----------------
#define SWZ(row, cb) ((cb) ^ (((((row) >> 3) ^ (row)) & 7) << 4))

__global__ __launch_bounds__(256)
void fc1_kernel(const float* __restrict__ x, const int* __restrict__ tok_idx,
                const float* __restrict__ w1, const float* __restrict__ b1,
                unsigned short* __restrict__ h) {
  const int bx = blockIdx.x;
  const int e  = bx >> 5;
  const int mt = (bx >> 3) & 3;
  const int nt = bx & 7;
  const int m0 = mt * 128, n0 = nt * 128;
  const int t = threadIdx.x;
  const int lane = t & 63, wave = t >> 6;
  const int wm = wave >> 1, wn = wave & 1;

  __shared__ __align__(16) unsigned short Asm[128 * 64];
  __shared__ __align__(16) unsigned short Bsm[128 * 64];

  const int arq = t & 31, akq = t >> 5;
  int tokr[4];
#pragma unroll
  for (int j = 0; j < 4; ++j) tokr[j] = tok_idx[e * CAP + m0 + arq * 4 + j];
  const int nq = t & 31, kq = t >> 5;
  const float* bptr = w1 + (size_t)e * DIM * HID + n0 + nq * 4;

  f32x4 acc[4][4] = {};

  for (int k0 = 0; k0 < DIM; k0 += 64) {
    float4 av0[4], av1[4];
#pragma unroll
    for (int j = 0; j < 4; ++j) {
      const float* ap = x + (size_t)tokr[j] * DIM + k0 + akq * 8;
      av0[j] = *(const float4*)(ap);
      av1[j] = *(const float4*)(ap + 4);
    }
    float4 bv[8];
#pragma unroll
    for (int kk = 0; kk < 8; ++kk)
      bv[kk] = *(const float4*)(bptr + (size_t)(k0 + kq * 8 + kk) * HID);
    __syncthreads();
#pragma unroll
    for (int j = 0; j < 4; ++j) {
      const int row = arq * 4 + j;
      ushort4 w0, w1v;
      w0.x = f2bf(av0[j].x); w0.y = f2bf(av0[j].y); w0.z = f2bf(av0[j].z); w0.w = f2bf(av0[j].w);
      w1v.x = f2bf(av1[j].x); w1v.y = f2bf(av1[j].y); w1v.z = f2bf(av1[j].z); w1v.w = f2bf(av1[j].w);
      *(ushort4*)((char*)Asm + row * 128 + SWZ(row, (akq * 8 + 0) * 2)) = w0;
      *(ushort4*)((char*)Asm + row * 128 + SWZ(row, (akq * 8 + 4) * 2)) = w1v;
    }
#pragma unroll
    for (int g = 0; g < 2; ++g) {
#pragma unroll
      for (int j = 0; j < 4; ++j) {   // transpose w1 tile into [n][k]
        ushort4 wv;
        wv.x = f2bf(GET4(bv[g * 4 + 0], j));
        wv.y = f2bf(GET4(bv[g * 4 + 1], j));
        wv.z = f2bf(GET4(bv[g * 4 + 2], j));
        wv.w = f2bf(GET4(bv[g * 4 + 3], j));
        const int row = nq * 4 + j;
        const int cb = (kq * 8 + g * 4) * 2;
        *(ushort4*)((char*)Bsm + row * 128 + SWZ(row, cb)) = wv;
      }
    }
    __syncthreads();
#pragma unroll
    for (int ks = 0; ks < 2; ++ks) {
      bf16x8 af[4], bf[4];
#pragma unroll
      for (int mi = 0; mi < 4; ++mi) {
        const int row = wm * 64 + mi * 16 + (lane & 15);
        const int cb = ks * 64 + (lane >> 4) * 16;
        af[mi] = *(const bf16x8*)((const char*)Asm + row * 128 + SWZ(row, cb));
      }
#pragma unroll
      for (int ni = 0; ni < 4; ++ni) {
        const int row = wn * 64 + ni * 16 + (lane & 15);
        const int cb = ks * 64 + (lane >> 4) * 16;
        bf[ni] = *(const bf16x8*)((const char*)Bsm + row * 128 + SWZ(row, cb));
      }
#pragma unroll
      for (int mi = 0; mi < 4; ++mi)
#pragma unroll
        for (int ni = 0; ni < 4; ++ni)
          acc[mi][ni] = __builtin_amdgcn_mfma_f32_16x16x32_bf16(af[mi], bf[ni], acc[mi][ni], 0, 0, 0);
    }
  }
  const int lr = lane >> 4, lc = lane & 15;
#pragma unroll
  for (int ni = 0; ni < 4; ++ni) {
    const int n_l = wn * 64 + ni * 16 + lc;
    const float bias = b1[e * HID + n0 + n_l];
#pragma unroll
    for (int mi = 0; mi < 4; ++mi) {
#pragma unroll
      for (int j = 0; j < 4; ++j) {
        const int m_l = wm * 64 + mi * 16 + lr * 4 + j;
        float v = acc[mi][ni][j] + bias;
        float gv = 0.5f * v * (1.0f + erff(v * 0.70710678118654752f));
        h[((size_t)(e * CAP + m0 + m_l)) * HID + (n0 + n_l)] = f2bf(gv);
      }
    }
  }
}

__global__ __launch_bounds__(256)
void fc2_kernel(const unsigned short* __restrict__ h, const float* __restrict__ w2,
                const float* __restrict__ b2, const int* __restrict__ tok_idx,
                const float* __restrict__ expw, float* __restrict__ out) {
  const int bx = blockIdx.x;
  const int e  = bx >> 4;
  const int mt = (bx >> 2) & 3;
  const int nt = bx & 3;
  const int m0 = mt * 128, n0 = nt * 128;
  const int t = threadIdx.x;
  const int lane = t & 63, wave = t >> 6;
  const int wm = wave >> 1, wn = wave & 1;

  __shared__ __align__(16) unsigned short Asm[128 * 64];
  __shared__ __align__(16) unsigned short Bsm[128 * 64];

  const int arq = t & 31, akq = t >> 5;
  const unsigned short* aptr0 = h + ((size_t)(e * CAP + m0 + arq * 4)) * HID + akq * 8;
  const int nq = t & 31, kq = t >> 5;
  const float* bptr = w2 + (size_t)e * HID * DIM + n0 + nq * 4;

  f32x4 acc[4][4] = {};

  for (int k0 = 0; k0 < HID; k0 += 64) {
    uint4 av[4];
#pragma unroll
    for (int j = 0; j < 4; ++j)
      av[j] = *(const uint4*)(aptr0 + (size_t)j * HID + k0);
    float4 bv[8];
#pragma unroll
    for (int kk = 0; kk < 8; ++kk)
      bv[kk] = *(const float4*)(bptr + (size_t)(k0 + kq * 8 + kk) * DIM);
    __syncthreads();
#pragma unroll
    for (int j = 0; j < 4; ++j) {
      const int row = arq * 4 + j;
      *(uint4*)((char*)Asm + row * 128 + SWZ(row, akq * 16)) = av[j];
    }
#pragma unroll
    for (int g = 0; g < 2; ++g) {
#pragma unroll
      for (int j = 0; j < 4; ++j) {
        ushort4 wv;
        wv.x = f2bf(GET4(bv[g * 4 + 0], j));
        wv.y = f2bf(GET4(bv[g * 4 + 1], j));
        wv.z = f2bf(GET4(bv[g * 4 + 2], j));
        wv.w = f2bf(GET4(bv[g * 4 + 3], j));
        const int row = nq * 4 + j;
        const int cb = (kq * 8 + g * 4) * 2;
        *(ushort4*)((char*)Bsm + row * 128 + SWZ(row, cb)) = wv;
      }
    }
    __syncthreads();
#pragma unroll
    for (int ks = 0; ks < 2; ++ks) {
      bf16x8 af[4], bf[4];
#pragma unroll
      for (int mi = 0; mi < 4; ++mi) {
        const int row = wm * 64 + mi * 16 + (lane & 15);
        const int cb = ks * 64 + (lane >> 4) * 16;
        af[mi] = *(const bf16x8*)((const char*)Asm + row * 128 + SWZ(row, cb));
      }
#pragma unroll
      for (int ni = 0; ni < 4; ++ni) {
        const int row = wn * 64 + ni * 16 + (lane & 15);
        const int cb = ks * 64 + (lane >> 4) * 16;
        bf[ni] = *(const bf16x8*)((const char*)Bsm + row * 128 + SWZ(row, cb));
      }
#pragma unroll
      for (int mi = 0; mi < 4; ++mi)
#pragma unroll
        for (int ni = 0; ni < 4; ++ni)
          acc[mi][ni] = __builtin_amdgcn_mfma_f32_16x16x32_bf16(af[mi], bf[ni], acc[mi][ni], 0, 0, 0);
    }
  }
  const int lr = lane >> 4, lc = lane & 15;
  int   tokm[4][4];
  float wgt[4][4];
#pragma unroll
  for (int mi = 0; mi < 4; ++mi)
#pragma unroll
    for (int j = 0; j < 4; ++j) {
      const int m_l = wm * 64 + mi * 16 + lr * 4 + j;
      tokm[mi][j] = tok_idx[e * CAP + m0 + m_l];
      wgt[mi][j]  = expw[e * CAP + m0 + m_l];
    }
#pragma unroll
  for (int ni = 0; ni < 4; ++ni) {
    const int n_l = wn * 64 + ni * 16 + lc;
    const float bias = b2[e * DIM + n0 + n_l];
#pragma unroll
    for (int mi = 0; mi < 4; ++mi)
#pragma unroll
      for (int j = 0; j < 4; ++j) {
        float v = (acc[mi][ni][j] + bias) * wgt[mi][j];
        atomicAdd(out + (size_t)tokm[mi][j] * DIM + (n0 + n_l), v);
      }
  }
}

extern "C" void kernel_launch(void* const* d_in, const int* in_sizes, int n_in,
                              void* d_out, int out_size, void* d_ws, size_t ws_size,
                              hipStream_t stream) {
  const float* x  = (const float*)d_in[0];
  const float* rw = (const float*)d_in[1];
  const float* w1 = (const float*)d_in[2];
  const float* b1 = (const float*)d_in[3];
  const float* w2 = (const float*)d_in[4];
  const float* b2 = (const float*)d_in[5];
  float* out = (float*)d_out;

  char* ws = (char*)d_ws;
  float* logits = (float*)ws;                                   // 8 MB
  int*   toki   = (int*)(ws + (8u << 20));                      // 128 KB
  float* ew     = (float*)(ws + (8u << 20) + (128u << 10));     // 128 KB
  unsigned short* h = (unsigned short*)(ws + (8u << 20) + (256u << 10)); // 64 MB

  (void)hipMemsetAsync(d_out, 0, (size_t)out_size * sizeof(float), stream);
  router_kernel<<<dim3(512), dim3(256), 0, stream>>>(x, rw, logits);
  topk_kernel<<<dim3(64), dim3(1024), 0, stream>>>(logits, toki, ew, out + (size_t)N_TOK * DIM);
  fc1_kernel<<<dim3(2048), dim3(256), 0, stream>>>(x, toki, w1, b1, h);
  fc2_kernel<<<dim3(1024), dim3(256), 0, stream>>>(h, w2, b2, toki, ew, out);
}

// Round 5
// 573.751 us; speedup vs baseline: 1.1904x; 1.1904x over previous
//
#include <hip/hip_runtime.h>
#include <math.h>

#define N_TOK 32768
#define DIM   512
#define NEXP  64
#define HID   1024
#define CAP   512

typedef float  f32x4  __attribute__((ext_vector_type(4)));
typedef short  bf16x8 __attribute__((ext_vector_type(8)));

#define GET4(v, jj) ((jj) == 0 ? (v).x : (jj) == 1 ? (v).y : (jj) == 2 ? (v).z : (v).w)

__device__ __forceinline__ unsigned short f2bf(float f) {
  unsigned u = __float_as_uint(f);
  u += 0x7FFFu + ((u >> 16) & 1u);   // RNE
  return (unsigned short)(u >> 16);
}
__device__ __forceinline__ unsigned enc_f(float f) {  // monotone f32 -> u32
  unsigned u = __float_as_uint(f);
  return (u & 0x80000000u) ? ~u : (u | 0x80000000u);
}
__device__ __forceinline__ float dec_f(unsigned k) {
  unsigned u = (k & 0x80000000u) ? (k & 0x7FFFFFFFu) : ~k;
  return __uint_as_float(u);
}

// ---------------- router: logitsT[e][n] = sum_d x[n][d]*rw[d][e], fp32 accum ----------------
// 1024 blocks x 256 thr; block = 32 tokens x 64 experts; thread = 2 tokens x 4 experts
// (8 independent fp32 chains -> latency hidden; 4096 waves -> 16 waves/CU)
__global__ __launch_bounds__(256)
void router_kernel(const float* __restrict__ x, const float* __restrict__ rw,
                   float* __restrict__ logitsT) {
  const int t = threadIdx.x;
  const int n0 = blockIdx.x * 32 + (t >> 4) * 2;   // this thread's 2 tokens
  const int e0 = (t & 15) * 4;                     // this thread's 4 experts
  float acc[8];
#pragma unroll
  for (int i = 0; i < 8; ++i) acc[i] = 0.f;
  const float* xr0 = x + (size_t)(n0 + 0) * DIM;
  const float* xr1 = x + (size_t)(n0 + 1) * DIM;
  for (int k0 = 0; k0 < DIM; k0 += 4) {
    float4 a0 = *(const float4*)(xr0 + k0);
    float4 a1 = *(const float4*)(xr1 + k0);
#pragma unroll
    for (int kk = 0; kk < 4; ++kk) {
      float4 b = *(const float4*)(rw + (size_t)(k0 + kk) * NEXP + e0);
      float d0 = GET4(a0, kk);
      float d1 = GET4(a1, kk);
      acc[0] += d0 * b.x; acc[1] += d0 * b.y; acc[2] += d0 * b.z; acc[3] += d0 * b.w;
      acc[4] += d1 * b.x; acc[5] += d1 * b.y; acc[6] += d1 * b.z; acc[7] += d1 * b.w;
    }
  }
#pragma unroll
  for (int j = 0; j < 2; ++j)
#pragma unroll
    for (int ee = 0; ee < 4; ++ee)
      logitsT[(size_t)(e0 + ee) * N_TOK + (n0 + j)] = acc[j * 4 + ee];
}

// ------------- per-expert max/sumexp + exact radix top-512 (all loops bounded) -------------
__global__ __launch_bounds__(1024)
void topk_kernel(const float* __restrict__ logitsT, int* __restrict__ tok_idx,
                 float* __restrict__ expw, float* __restrict__ auxout) {
  const int e = blockIdx.x;
  const int t = threadIdx.x;
  const float* row = logitsT + (size_t)e * N_TOK;

  unsigned key[32];          // token n = j*1024 + t
#pragma unroll
  for (int j = 0; j < 32; ++j) key[j] = enc_f(row[j * 1024 + t]);

  __shared__ unsigned ured[1024];
  __shared__ float    fred[1024];
  __shared__ unsigned hist[256];
  __shared__ unsigned sh_chosen, sh_rem, sh_x, sh_pos;

  // block max (deterministic tree)
  unsigned km = 0;
#pragma unroll
  for (int j = 0; j < 32; ++j) km = key[j] > km ? key[j] : km;
  ured[t] = km;
  __syncthreads();
  for (int s = 512; s > 0; s >>= 1) {
    if (t < s) { unsigned o = ured[t + s]; if (o > ured[t]) ured[t] = o; }
    __syncthreads();
  }
  const float m = dec_f(ured[0]);

  float ssum = 0.f;
#pragma unroll
  for (int j = 0; j < 32; ++j) ssum += expf(dec_f(key[j]) - m);
  fred[t] = ssum;
  __syncthreads();
  for (int s = 512; s > 0; s >>= 1) {
    if (t < s) fred[t] += fred[t + s];
    __syncthreads();
  }
  const float invZ = 1.0f / fred[0];

  // radix select (4 passes of 8 bits): exact key of the 512th-largest logit
  if (t == 0) sh_rem = CAP;
  __syncthreads();
  unsigned live = 0xFFFFFFFFu;
  unsigned prefix = 0;
  for (int pass = 0; pass < 4; ++pass) {
    const int shift = 24 - pass * 8;
    if (t < 256) hist[t] = 0;
    __syncthreads();
#pragma unroll
    for (int j = 0; j < 32; ++j)
      if (live & (1u << j)) atomicAdd(&hist[(key[j] >> shift) & 0xFFu], 1u);
    __syncthreads();
    if (t == 0) {
      unsigned need = sh_rem, accum = 0;
      int found = 0;
      for (int b = 255; b >= 0; --b) {
        unsigned cn = hist[b];
        if (!found) {
          if (accum + cn >= need) { sh_chosen = (unsigned)b; sh_rem = need - accum; found = 1; }
          else accum += cn;
        }
      }
    }
    __syncthreads();
    const unsigned ch = sh_chosen;
#pragma unroll
    for (int j = 0; j < 32; ++j)
      if (((key[j] >> shift) & 0xFFu) != ch) live &= ~(1u << j);
    prefix = (prefix << 8) | ch;
    __syncthreads();
  }
  const unsigned ustar = prefix;   // `live` now marks keys == ustar

  // emit all strictly-greater keys
  if (t == 0) sh_pos = 0;
  __syncthreads();
#pragma unroll
  for (int j = 0; j < 32; ++j) {
    if (key[j] > ustar) {
      unsigned p = atomicAdd(&sh_pos, 1u);
      tok_idx[e * CAP + p] = j * 1024 + t;
      expw[e * CAP + p] = expf(dec_f(key[j]) - m) * invZ;
    }
  }
  __syncthreads();
  const unsigned padv = CAP - sh_pos;  // #ties to take, smallest token index first

  // two bounded radix passes over token indices among ties: padv-th smallest index X
  if (t < 256) hist[t] = 0;
  __syncthreads();
#pragma unroll
  for (int j = 0; j < 32; ++j)
    if (live & (1u << j)) atomicAdd(&hist[(j * 1024 + t) >> 7], 1u);
  __syncthreads();
  if (t == 0) {
    unsigned accum = 0;
    int found = 0;
    for (int b = 0; b < 256; ++b) {
      unsigned cn = hist[b];
      if (!found) {
        if (accum + cn >= padv) { sh_chosen = (unsigned)b; sh_rem = padv - accum; found = 1; }
        else accum += cn;
      }
    }
  }
  __syncthreads();
  const unsigned hb = sh_chosen, rem = sh_rem;
  if (t < 256) hist[t] = 0;
  __syncthreads();
#pragma unroll
  for (int j = 0; j < 32; ++j)
    if (live & (1u << j)) {
      int n = j * 1024 + t;
      if ((unsigned)(n >> 7) == hb) atomicAdd(&hist[n & 127], 1u);
    }
  __syncthreads();
  if (t == 0) {
    unsigned accum = 0;
    int found = 0;
    for (int b = 0; b < 128; ++b) {
      unsigned cn = hist[b];
      if (!found) {
        if (accum + cn >= rem) { sh_x = (hb << 7) | (unsigned)b; found = 1; }
        else accum += cn;
      }
    }
  }
  __syncthreads();
  const int X = (int)sh_x;                   // padv-th smallest tie index
#pragma unroll
  for (int j = 0; j < 32; ++j)
    if (live & (1u << j)) {
      int n = j * 1024 + t;
      if (n <= X) {
        unsigned p = atomicAdd(&sh_pos, 1u);
        tok_idx[e * CAP + p] = n;
        expw[e * CAP + p] = expf(dec_f(key[j]) - m) * invZ;
      }
    }
  if (e == 0 && t == 0) { auxout[0] = 2.44140625e-4f; auxout[1] = 0.015625f; }
}

// ---------------- FFN GEMMs: 128x128 tile, BK=64, bf16 MFMA 16x16x32 ----------------
#define SWZ(row, cb) ((cb) ^ (((((row) >> 3) ^ (row)) & 7) << 4))

__global__ __launch_bounds__(256)
void fc1_kernel(const float* __restrict__ x, const int* __restrict__ tok_idx,
                const float* __restrict__ w1, const float* __restrict__ b1,
                unsigned short* __restrict__ h) {
  const int bx = blockIdx.x;
  const int e  = bx >> 5;
  const int mt = (bx >> 3) & 3;
  const int nt = bx & 7;
  const int m0 = mt * 128, n0 = nt * 128;
  const int t = threadIdx.x;
  const int lane = t & 63, wave = t >> 6;
  const int wm = wave >> 1, wn = wave & 1;

  __shared__ __align__(16) unsigned short Asm[128 * 64];
  __shared__ __align__(16) unsigned short Bsm[128 * 64];

  const int arq = t & 31, akq = t >> 5;
  int tokr[4];
#pragma unroll
  for (int j = 0; j < 4; ++j) tokr[j] = tok_idx[e * CAP + m0 + arq * 4 + j];
  const int nq = t & 31, kq = t >> 5;
  const float* bptr = w1 + (size_t)e * DIM * HID + n0 + nq * 4;

  f32x4 acc[4][4] = {};

  for (int k0 = 0; k0 < DIM; k0 += 64) {
    float4 av0[4], av1[4];
#pragma unroll
    for (int j = 0; j < 4; ++j) {
      const float* ap = x + (size_t)tokr[j] * DIM + k0 + akq * 8;
      av0[j] = *(const float4*)(ap);
      av1[j] = *(const float4*)(ap + 4);
    }
    float4 bv[8];
#pragma unroll
    for (int kk = 0; kk < 8; ++kk)
      bv[kk] = *(const float4*)(bptr + (size_t)(k0 + kq * 8 + kk) * HID);
    __syncthreads();
#pragma unroll
    for (int j = 0; j < 4; ++j) {
      const int row = arq * 4 + j;
      ushort4 w0, w1v;
      w0.x = f2bf(av0[j].x); w0.y = f2bf(av0[j].y); w0.z = f2bf(av0[j].z); w0.w = f2bf(av0[j].w);
      w1v.x = f2bf(av1[j].x); w1v.y = f2bf(av1[j].y); w1v.z = f2bf(av1[j].z); w1v.w = f2bf(av1[j].w);
      *(ushort4*)((char*)Asm + row * 128 + SWZ(row, (akq * 8 + 0) * 2)) = w0;
      *(ushort4*)((char*)Asm + row * 128 + SWZ(row, (akq * 8 + 4) * 2)) = w1v;
    }
#pragma unroll
    for (int g = 0; g < 2; ++g) {
#pragma unroll
      for (int j = 0; j < 4; ++j) {   // transpose w1 tile into [n][k]
        ushort4 wv;
        wv.x = f2bf(GET4(bv[g * 4 + 0], j));
        wv.y = f2bf(GET4(bv[g * 4 + 1], j));
        wv.z = f2bf(GET4(bv[g * 4 + 2], j));
        wv.w = f2bf(GET4(bv[g * 4 + 3], j));
        const int row = nq * 4 + j;
        const int cb = (kq * 8 + g * 4) * 2;
        *(ushort4*)((char*)Bsm + row * 128 + SWZ(row, cb)) = wv;
      }
    }
    __syncthreads();
#pragma unroll
    for (int ks = 0; ks < 2; ++ks) {
      bf16x8 af[4], bf[4];
#pragma unroll
      for (int mi = 0; mi < 4; ++mi) {
        const int row = wm * 64 + mi * 16 + (lane & 15);
        const int cb = ks * 64 + (lane >> 4) * 16;
        af[mi] = *(const bf16x8*)((const char*)Asm + row * 128 + SWZ(row, cb));
      }
#pragma unroll
      for (int ni = 0; ni < 4; ++ni) {
        const int row = wn * 64 + ni * 16 + (lane & 15);
        const int cb = ks * 64 + (lane >> 4) * 16;
        bf[ni] = *(const bf16x8*)((const char*)Bsm + row * 128 + SWZ(row, cb));
      }
#pragma unroll
      for (int mi = 0; mi < 4; ++mi)
#pragma unroll
        for (int ni = 0; ni < 4; ++ni)
          acc[mi][ni] = __builtin_amdgcn_mfma_f32_16x16x32_bf16(af[mi], bf[ni], acc[mi][ni], 0, 0, 0);
    }
  }
  const int lr = lane >> 4, lc = lane & 15;
#pragma unroll
  for (int ni = 0; ni < 4; ++ni) {
    const int n_l = wn * 64 + ni * 16 + lc;
    const float bias = b1[e * HID + n0 + n_l];
#pragma unroll
    for (int mi = 0; mi < 4; ++mi) {
#pragma unroll
      for (int j = 0; j < 4; ++j) {
        const int m_l = wm * 64 + mi * 16 + lr * 4 + j;
        float v = acc[mi][ni][j] + bias;
        float gv = 0.5f * v * (1.0f + erff(v * 0.70710678118654752f));
        h[((size_t)(e * CAP + m0 + m_l)) * HID + (n0 + n_l)] = f2bf(gv);
      }
    }
  }
}

__global__ __launch_bounds__(256)
void fc2_kernel(const unsigned short* __restrict__ h, const float* __restrict__ w2,
                const float* __restrict__ b2, const int* __restrict__ tok_idx,
                const float* __restrict__ expw, float* __restrict__ out) {
  const int bx = blockIdx.x;
  const int e  = bx >> 4;
  const int mt = (bx >> 2) & 3;
  const int nt = bx & 3;
  const int m0 = mt * 128, n0 = nt * 128;
  const int t = threadIdx.x;
  const int lane = t & 63, wave = t >> 6;
  const int wm = wave >> 1, wn = wave & 1;

  __shared__ __align__(16) unsigned short Asm[128 * 64];
  __shared__ __align__(16) unsigned short Bsm[128 * 64];

  const int arq = t & 31, akq = t >> 5;
  const unsigned short* aptr0 = h + ((size_t)(e * CAP + m0 + arq * 4)) * HID + akq * 8;
  const int nq = t & 31, kq = t >> 5;
  const float* bptr = w2 + (size_t)e * HID * DIM + n0 + nq * 4;

  f32x4 acc[4][4] = {};

  for (int k0 = 0; k0 < HID; k0 += 64) {
    uint4 av[4];
#pragma unroll
    for (int j = 0; j < 4; ++j)
      av[j] = *(const uint4*)(aptr0 + (size_t)j * HID + k0);
    float4 bv[8];
#pragma unroll
    for (int kk = 0; kk < 8; ++kk)
      bv[kk] = *(const float4*)(bptr + (size_t)(k0 + kq * 8 + kk) * DIM);
    __syncthreads();
#pragma unroll
    for (int j = 0; j < 4; ++j) {
      const int row = arq * 4 + j;
      *(uint4*)((char*)Asm + row * 128 + SWZ(row, akq * 16)) = av[j];
    }
#pragma unroll
    for (int g = 0; g < 2; ++g) {
#pragma unroll
      for (int j = 0; j < 4; ++j) {
        ushort4 wv;
        wv.x = f2bf(GET4(bv[g * 4 + 0], j));
        wv.y = f2bf(GET4(bv[g * 4 + 1], j));
        wv.z = f2bf(GET4(bv[g * 4 + 2], j));
        wv.w = f2bf(GET4(bv[g * 4 + 3], j));
        const int row = nq * 4 + j;
        const int cb = (kq * 8 + g * 4) * 2;
        *(ushort4*)((char*)Bsm + row * 128 + SWZ(row, cb)) = wv;
      }
    }
    __syncthreads();
#pragma unroll
    for (int ks = 0; ks < 2; ++ks) {
      bf16x8 af[4], bf[4];
#pragma unroll
      for (int mi = 0; mi < 4; ++mi) {
        const int row = wm * 64 + mi * 16 + (lane & 15);
        const int cb = ks * 64 + (lane >> 4) * 16;
        af[mi] = *(const bf16x8*)((const char*)Asm + row * 128 + SWZ(row, cb));
      }
#pragma unroll
      for (int ni = 0; ni < 4; ++ni) {
        const int row = wn * 64 + ni * 16 + (lane & 15);
        const int cb = ks * 64 + (lane >> 4) * 16;
        bf[ni] = *(const bf16x8*)((const char*)Bsm + row * 128 + SWZ(row, cb));
      }
#pragma unroll
      for (int mi = 0; mi < 4; ++mi)
#pragma unroll
        for (int ni = 0; ni < 4; ++ni)
          acc[mi][ni] = __builtin_amdgcn_mfma_f32_16x16x32_bf16(af[mi], bf[ni], acc[mi][ni], 0, 0, 0);
    }
  }
  const int lr = lane >> 4, lc = lane & 15;
  int   tokm[4][4];
  float wgt[4][4];
#pragma unroll
  for (int mi = 0; mi < 4; ++mi)
#pragma unroll
    for (int j = 0; j < 4; ++j) {
      const int m_l = wm * 64 + mi * 16 + lr * 4 + j;
      tokm[mi][j] = tok_idx[e * CAP + m0 + m_l];
      wgt[mi][j]  = expw[e * CAP + m0 + m_l];
    }
#pragma unroll
  for (int ni = 0; ni < 4; ++ni) {
    const int n_l = wn * 64 + ni * 16 + lc;
    const float bias = b2[e * DIM + n0 + n_l];
#pragma unroll
    for (int mi = 0; mi < 4; ++mi)
#pragma unroll
      for (int j = 0; j < 4; ++j) {
        float v = (acc[mi][ni][j] + bias) * wgt[mi][j];
        atomicAdd(out + (size_t)tokm[mi][j] * DIM + (n0 + n_l), v);
      }
  }
}

extern "C" void kernel_launch(void* const* d_in, const int* in_sizes, int n_in,
                              void* d_out, int out_size, void* d_ws, size_t ws_size,
                              hipStream_t stream) {
  const float* x  = (const float*)d_in[0];
  const float* rw = (const float*)d_in[1];
  const float* w1 = (const float*)d_in[2];
  const float* b1 = (const float*)d_in[3];
  const float* w2 = (const float*)d_in[4];
  const float* b2 = (const float*)d_in[5];
  float* out = (float*)d_out;

  char* ws = (char*)d_ws;
  float* logits = (float*)ws;                                   // 8 MB
  int*   toki   = (int*)(ws + (8u << 20));                      // 128 KB
  float* ew     = (float*)(ws + (8u << 20) + (128u << 10));     // 128 KB
  unsigned short* h = (unsigned short*)(ws + (8u << 20) + (256u << 10)); // 64 MB

  (void)hipMemsetAsync(d_out, 0, (size_t)out_size * sizeof(float), stream);
  router_kernel<<<dim3(1024), dim3(256), 0, stream>>>(x, rw, logits);
  topk_kernel<<<dim3(64), dim3(1024), 0, stream>>>(logits, toki, ew, out + (size_t)N_TOK * DIM);
  fc1_kernel<<<dim3(2048), dim3(256), 0, stream>>>(x, toki, w1, b1, h);
  fc2_kernel<<<dim3(1024), dim3(256), 0, stream>>>(h, w2, b2, toki, ew, out);
}

// Round 6
// 527.008 us; speedup vs baseline: 1.2960x; 1.0887x over previous
//
#include <hip/hip_runtime.h>
#include <math.h>

#define N_TOK 32768
#define DIM   512
#define NEXP  64
#define HID   1024
#define CAP   512

typedef float  f32x4  __attribute__((ext_vector_type(4)));
typedef short  bf16x8 __attribute__((ext_vector_type(8)));
typedef unsigned short u16;

#define GET4(v, jj) ((jj) == 0 ? (v).x : (jj) == 1 ? (v).y : (jj) == 2 ? (v).z : (v).w)

__device__ __forceinline__ u16 f2bf(float f) {
  unsigned u = __float_as_uint(f);
  u += 0x7FFFu + ((u >> 16) & 1u);   // RNE
  return (u16)(u >> 16);
}
__device__ __forceinline__ unsigned enc_f(float f) {  // monotone f32 -> u32
  unsigned u = __float_as_uint(f);
  return (u & 0x80000000u) ? ~u : (u | 0x80000000u);
}
__device__ __forceinline__ float dec_f(unsigned k) {
  unsigned u = (k & 0x80000000u) ? (k & 0x7FFFFFFFu) : ~k;
  return __uint_as_float(u);
}
__device__ __forceinline__ void gl16(const u16* g, u16* l) {
  __builtin_amdgcn_global_load_lds(
      (const __attribute__((address_space(1))) unsigned int*)g,
      (__attribute__((address_space(3))) unsigned int*)l, 16, 0, 0);
}

// ---------------- router: logitsT[e][n] = sum_d x[n][d]*rw[d][e], fp32 accum ----------------
__global__ __launch_bounds__(256)
void router_kernel(const float* __restrict__ x, const float* __restrict__ rw,
                   float* __restrict__ logitsT) {
  const int t = threadIdx.x;
  const int n0 = blockIdx.x * 32 + (t >> 4) * 2;
  const int e0 = (t & 15) * 4;
  float acc[8];
#pragma unroll
  for (int i = 0; i < 8; ++i) acc[i] = 0.f;
  const float* xr0 = x + (size_t)(n0 + 0) * DIM;
  const float* xr1 = x + (size_t)(n0 + 1) * DIM;
  for (int k0 = 0; k0 < DIM; k0 += 4) {
    float4 a0 = *(const float4*)(xr0 + k0);
    float4 a1 = *(const float4*)(xr1 + k0);
#pragma unroll
    for (int kk = 0; kk < 4; ++kk) {
      float4 b = *(const float4*)(rw + (size_t)(k0 + kk) * NEXP + e0);
      float d0 = GET4(a0, kk);
      float d1 = GET4(a1, kk);
      acc[0] += d0 * b.x; acc[1] += d0 * b.y; acc[2] += d0 * b.z; acc[3] += d0 * b.w;
      acc[4] += d1 * b.x; acc[5] += d1 * b.y; acc[6] += d1 * b.z; acc[7] += d1 * b.w;
    }
  }
#pragma unroll
  for (int j = 0; j < 2; ++j)
#pragma unroll
    for (int ee = 0; ee < 4; ++ee)
      logitsT[(size_t)(e0 + ee) * N_TOK + (n0 + j)] = acc[j * 4 + ee];
}

// ------------- per-expert max/sumexp + exact radix top-512 (all loops bounded) -------------
__global__ __launch_bounds__(1024)
void topk_kernel(const float* __restrict__ logitsT, int* __restrict__ tok_idx,
                 float* __restrict__ expw, float* __restrict__ auxout) {
  const int e = blockIdx.x;
  const int t = threadIdx.x;
  const float* row = logitsT + (size_t)e * N_TOK;

  unsigned key[32];          // token n = j*1024 + t
#pragma unroll
  for (int j = 0; j < 32; ++j) key[j] = enc_f(row[j * 1024 + t]);

  __shared__ unsigned ured[1024];
  __shared__ float    fred[1024];
  __shared__ unsigned hist[256];
  __shared__ unsigned sh_chosen, sh_rem, sh_x, sh_pos;

  unsigned km = 0;
#pragma unroll
  for (int j = 0; j < 32; ++j) km = key[j] > km ? key[j] : km;
  ured[t] = km;
  __syncthreads();
  for (int s = 512; s > 0; s >>= 1) {
    if (t < s) { unsigned o = ured[t + s]; if (o > ured[t]) ured[t] = o; }
    __syncthreads();
  }
  const float m = dec_f(ured[0]);

  float ssum = 0.f;
#pragma unroll
  for (int j = 0; j < 32; ++j) ssum += expf(dec_f(key[j]) - m);
  fred[t] = ssum;
  __syncthreads();
  for (int s = 512; s > 0; s >>= 1) {
    if (t < s) fred[t] += fred[t + s];
    __syncthreads();
  }
  const float invZ = 1.0f / fred[0];

  if (t == 0) sh_rem = CAP;
  __syncthreads();
  unsigned live = 0xFFFFFFFFu;
  unsigned prefix = 0;
  for (int pass = 0; pass < 4; ++pass) {
    const int shift = 24 - pass * 8;
    if (t < 256) hist[t] = 0;
    __syncthreads();
#pragma unroll
    for (int j = 0; j < 32; ++j)
      if (live & (1u << j)) atomicAdd(&hist[(key[j] >> shift) & 0xFFu], 1u);
    __syncthreads();
    if (t == 0) {
      unsigned need = sh_rem, accum = 0;
      int found = 0;
      for (int b = 255; b >= 0; --b) {
        unsigned cn = hist[b];
        if (!found) {
          if (accum + cn >= need) { sh_chosen = (unsigned)b; sh_rem = need - accum; found = 1; }
          else accum += cn;
        }
      }
    }
    __syncthreads();
    const unsigned ch = sh_chosen;
#pragma unroll
    for (int j = 0; j < 32; ++j)
      if (((key[j] >> shift) & 0xFFu) != ch) live &= ~(1u << j);
    prefix = (prefix << 8) | ch;
    __syncthreads();
  }
  const unsigned ustar = prefix;

  if (t == 0) sh_pos = 0;
  __syncthreads();
#pragma unroll
  for (int j = 0; j < 32; ++j) {
    if (key[j] > ustar) {
      unsigned p = atomicAdd(&sh_pos, 1u);
      tok_idx[e * CAP + p] = j * 1024 + t;
      expw[e * CAP + p] = expf(dec_f(key[j]) - m) * invZ;
    }
  }
  __syncthreads();
  const unsigned padv = CAP - sh_pos;

  if (t < 256) hist[t] = 0;
  __syncthreads();
#pragma unroll
  for (int j = 0; j < 32; ++j)
    if (live & (1u << j)) atomicAdd(&hist[(j * 1024 + t) >> 7], 1u);
  __syncthreads();
  if (t == 0) {
    unsigned accum = 0;
    int found = 0;
    for (int b = 0; b < 256; ++b) {
      unsigned cn = hist[b];
      if (!found) {
        if (accum + cn >= padv) { sh_chosen = (unsigned)b; sh_rem = padv - accum; found = 1; }
        else accum += cn;
      }
    }
  }
  __syncthreads();
  const unsigned hb = sh_chosen, rem = sh_rem;
  if (t < 256) hist[t] = 0;
  __syncthreads();
#pragma unroll
  for (int j = 0; j < 32; ++j)
    if (live & (1u << j)) {
      int n = j * 1024 + t;
      if ((unsigned)(n >> 7) == hb) atomicAdd(&hist[n & 127], 1u);
    }
  __syncthreads();
  if (t == 0) {
    unsigned accum = 0;
    int found = 0;
    for (int b = 0; b < 128; ++b) {
      unsigned cn = hist[b];
      if (!found) {
        if (accum + cn >= rem) { sh_x = (hb << 7) | (unsigned)b; found = 1; }
        else accum += cn;
      }
    }
  }
  __syncthreads();
  const int X = (int)sh_x;
#pragma unroll
  for (int j = 0; j < 32; ++j)
    if (live & (1u << j)) {
      int n = j * 1024 + t;
      if (n <= X) {
        unsigned p = atomicAdd(&sh_pos, 1u);
        tok_idx[e * CAP + p] = n;
        expw[e * CAP + p] = expf(dec_f(key[j]) - m) * invZ;
      }
    }
  if (e == 0 && t == 0) { auxout[0] = 2.44140625e-4f; auxout[1] = 0.015625f; }
}

// ---------------- prep: f32 -> bf16 cast ----------------
__global__ __launch_bounds__(256)
void cvt_bf16_kernel(const float* __restrict__ in, u16* __restrict__ outp) {
  size_t i = ((size_t)blockIdx.x * 256 + threadIdx.x) * 8;
  float4 v0 = *(const float4*)(in + i);
  float4 v1 = *(const float4*)(in + i + 4);
  uint4 o;
  o.x = f2bf(v0.x) | ((unsigned)f2bf(v0.y) << 16);
  o.y = f2bf(v0.z) | ((unsigned)f2bf(v0.w) << 16);
  o.z = f2bf(v1.x) | ((unsigned)f2bf(v1.y) << 16);
  o.w = f2bf(v1.z) | ((unsigned)f2bf(v1.w) << 16);
  *(uint4*)(outp + i) = o;
}

// ---------------- prep: per-expert transpose + cvt: f32 [E][R][C] -> bf16 [E][C][R] ----------------
__global__ __launch_bounds__(256)
void transpose_cvt_kernel(const float* __restrict__ in, u16* __restrict__ outp,
                          int R, int C) {
  __shared__ u16 tile[64][66];
  const int e = blockIdx.z;
  const int r0 = blockIdx.y * 64, c0 = blockIdx.x * 64;
  const int t = threadIdx.x;
  {
    const int r = t >> 2, cs = (t & 3) * 16;
    const float* ip = in + ((size_t)e * R + (r0 + r)) * C + c0 + cs;
#pragma unroll
    for (int q = 0; q < 4; ++q) {
      float4 v = *(const float4*)(ip + q * 4);
      tile[r][cs + q * 4 + 0] = f2bf(v.x);
      tile[r][cs + q * 4 + 1] = f2bf(v.y);
      tile[r][cs + q * 4 + 2] = f2bf(v.z);
      tile[r][cs + q * 4 + 3] = f2bf(v.w);
    }
  }
  __syncthreads();
  {
    const int c = t >> 2, rs = (t & 3) * 16;
    u16* op = outp + ((size_t)e * C + (c0 + c)) * R + r0 + rs;
    uint4 o0, o1;
    o0.x = tile[rs + 0][c]  | ((unsigned)tile[rs + 1][c]  << 16);
    o0.y = tile[rs + 2][c]  | ((unsigned)tile[rs + 3][c]  << 16);
    o0.z = tile[rs + 4][c]  | ((unsigned)tile[rs + 5][c]  << 16);
    o0.w = tile[rs + 6][c]  | ((unsigned)tile[rs + 7][c]  << 16);
    o1.x = tile[rs + 8][c]  | ((unsigned)tile[rs + 9][c]  << 16);
    o1.y = tile[rs + 10][c] | ((unsigned)tile[rs + 11][c] << 16);
    o1.z = tile[rs + 12][c] | ((unsigned)tile[rs + 13][c] << 16);
    o1.w = tile[rs + 14][c] | ((unsigned)tile[rs + 15][c] << 16);
    *(uint4*)(op) = o0;
    *(uint4*)(op + 8) = o1;
  }
}

// ===================== NEW bf16 GEMMs: global_load_lds staging =====================
// LDS linear [128 rows][64 k] bf16 per operand; global source pre-swizzled so that
// ds_read at byte (row*128 + (kb ^ ((row&7)<<4))) is bank-conflict-free (rule #21).

__global__ __launch_bounds__(256)
void fc1_bf(const u16* __restrict__ xb, const int* __restrict__ tok_idx,
            const u16* __restrict__ w1t, const float* __restrict__ b1,
            u16* __restrict__ h) {
  const int bx = blockIdx.x;
  const int e  = bx >> 5;
  const int mt = (bx >> 3) & 3;
  const int nt = bx & 7;
  const int m0 = mt * 128, n0 = nt * 128;
  const int t = threadIdx.x;
  const int lane = t & 63, wave = t >> 6;
  const int wm = wave >> 1, wn = wave & 1;

  __shared__ __align__(16) u16 Asm[128 * 64];
  __shared__ __align__(16) u16 Bsm[128 * 64];

  const int gk = ((lane & 7) ^ (lane >> 3)) * 8;   // inverse-swizzled k element offset
  const int rsub = lane >> 3;

  const u16* aS[4]; const u16* bS[4];
  u16* aD[4]; u16* bD[4];
#pragma unroll
  for (int i = 0; i < 4; ++i) {
    const int chunk = wave * 4 + i;
    const int arow = chunk * 8 + rsub;             // 0..127
    const int tok = tok_idx[e * CAP + m0 + arow];
    aS[i] = xb + (size_t)tok * DIM + gk;
    bS[i] = w1t + ((size_t)e * HID + n0 + arow) * DIM + gk;
    aD[i] = &Asm[chunk * 512];
    bD[i] = &Bsm[chunk * 512];
  }

  f32x4 acc[4][4] = {};
  const int lr = lane & 15, hi4 = lane >> 4;

  for (int k0 = 0; k0 < DIM; k0 += 64) {
#pragma unroll
    for (int i = 0; i < 4; ++i) {
      gl16(aS[i] + k0, aD[i]);
      gl16(bS[i] + k0, bD[i]);
    }
    __syncthreads();
#pragma unroll
    for (int ks = 0; ks < 2; ++ks) {
      bf16x8 af[4], bf[4];
#pragma unroll
      for (int mi = 0; mi < 4; ++mi) {
        const int row = wm * 64 + mi * 16 + lr;
        const int kb = ks * 64 + hi4 * 16;
        af[mi] = *(const bf16x8*)((const char*)Asm + row * 128 + (kb ^ ((row & 7) << 4)));
      }
#pragma unroll
      for (int ni = 0; ni < 4; ++ni) {
        const int row = wn * 64 + ni * 16 + lr;
        const int kb = ks * 64 + hi4 * 16;
        bf[ni] = *(const bf16x8*)((const char*)Bsm + row * 128 + (kb ^ ((row & 7) << 4)));
      }
#pragma unroll
      for (int mi = 0; mi < 4; ++mi)
#pragma unroll
        for (int ni = 0; ni < 4; ++ni)
          acc[mi][ni] = __builtin_amdgcn_mfma_f32_16x16x32_bf16(af[mi], bf[ni], acc[mi][ni], 0, 0, 0);
    }
    __syncthreads();
  }
  const int lq = lane >> 4, lc = lane & 15;
#pragma unroll
  for (int ni = 0; ni < 4; ++ni) {
    const int n_l = wn * 64 + ni * 16 + lc;
    const float bias = b1[e * HID + n0 + n_l];
#pragma unroll
    for (int mi = 0; mi < 4; ++mi) {
#pragma unroll
      for (int j = 0; j < 4; ++j) {
        const int m_l = wm * 64 + mi * 16 + lq * 4 + j;
        float v = acc[mi][ni][j] + bias;
        float gv = 0.5f * v * (1.0f + erff(v * 0.70710678118654752f));
        h[((size_t)(e * CAP + m0 + m_l)) * HID + (n0 + n_l)] = f2bf(gv);
      }
    }
  }
}

__global__ __launch_bounds__(256)
void fc2_bf(const u16* __restrict__ h, const u16* __restrict__ w2t,
            const float* __restrict__ b2, const int* __restrict__ tok_idx,
            const float* __restrict__ expw, float* __restrict__ out) {
  const int bx = blockIdx.x;
  const int e  = bx >> 4;
  const int mt = (bx >> 2) & 3;
  const int nt = bx & 3;
  const int m0 = mt * 128, n0 = nt * 128;
  const int t = threadIdx.x;
  const int lane = t & 63, wave = t >> 6;
  const int wm = wave >> 1, wn = wave & 1;

  __shared__ __align__(16) u16 Asm[128 * 64];
  __shared__ __align__(16) u16 Bsm[128 * 64];

  const int gk = ((lane & 7) ^ (lane >> 3)) * 8;
  const int rsub = lane >> 3;

  const u16* aS[4]; const u16* bS[4];
  u16* aD[4]; u16* bD[4];
#pragma unroll
  for (int i = 0; i < 4; ++i) {
    const int chunk = wave * 4 + i;
    const int arow = chunk * 8 + rsub;
    aS[i] = h + ((size_t)(e * CAP + m0 + arow)) * HID + gk;
    bS[i] = w2t + ((size_t)e * DIM + n0 + arow) * HID + gk;
    aD[i] = &Asm[chunk * 512];
    bD[i] = &Bsm[chunk * 512];
  }

  f32x4 acc[4][4] = {};
  const int lr = lane & 15, hi4 = lane >> 4;

  for (int k0 = 0; k0 < HID; k0 += 64) {
#pragma unroll
    for (int i = 0; i < 4; ++i) {
      gl16(aS[i] + k0, aD[i]);
      gl16(bS[i] + k0, bD[i]);
    }
    __syncthreads();
#pragma unroll
    for (int ks = 0; ks < 2; ++ks) {
      bf16x8 af[4], bf[4];
#pragma unroll
      for (int mi = 0; mi < 4; ++mi) {
        const int row = wm * 64 + mi * 16 + lr;
        const int kb = ks * 64 + hi4 * 16;
        af[mi] = *(const bf16x8*)((const char*)Asm + row * 128 + (kb ^ ((row & 7) << 4)));
      }
#pragma unroll
      for (int ni = 0; ni < 4; ++ni) {
        const int row = wn * 64 + ni * 16 + lr;
        const int kb = ks * 64 + hi4 * 16;
        bf[ni] = *(const bf16x8*)((const char*)Bsm + row * 128 + (kb ^ ((row & 7) << 4)));
      }
#pragma unroll
      for (int mi = 0; mi < 4; ++mi)
#pragma unroll
        for (int ni = 0; ni < 4; ++ni)
          acc[mi][ni] = __builtin_amdgcn_mfma_f32_16x16x32_bf16(af[mi], bf[ni], acc[mi][ni], 0, 0, 0);
    }
    __syncthreads();
  }
  const int lq = lane >> 4, lc = lane & 15;
  int   tokm[4][4];
  float wgt[4][4];
#pragma unroll
  for (int mi = 0; mi < 4; ++mi)
#pragma unroll
    for (int j = 0; j < 4; ++j) {
      const int m_l = wm * 64 + mi * 16 + lq * 4 + j;
      tokm[mi][j] = tok_idx[e * CAP + m0 + m_l];
      wgt[mi][j]  = expw[e * CAP + m0 + m_l];
    }
#pragma unroll
  for (int ni = 0; ni < 4; ++ni) {
    const int n_l = wn * 64 + ni * 16 + lc;
    const float bias = b2[e * DIM + n0 + n_l];
#pragma unroll
    for (int mi = 0; mi < 4; ++mi)
#pragma unroll
      for (int j = 0; j < 4; ++j) {
        float v = (acc[mi][ni][j] + bias) * wgt[mi][j];
        atomicAdd(out + (size_t)tokm[mi][j] * DIM + (n0 + n_l), v);
      }
  }
}

// ===================== OLD f32-input GEMMs (fallback if ws too small) =====================
#define SWZ(row, cb) ((cb) ^ (((((row) >> 3) ^ (row)) & 7) << 4))

__global__ __launch_bounds__(256)
void fc1_kernel(const float* __restrict__ x, const int* __restrict__ tok_idx,
                const float* __restrict__ w1, const float* __restrict__ b1,
                u16* __restrict__ h) {
  const int bx = blockIdx.x;
  const int e  = bx >> 5;
  const int mt = (bx >> 3) & 3;
  const int nt = bx & 7;
  const int m0 = mt * 128, n0 = nt * 128;
  const int t = threadIdx.x;
  const int lane = t & 63, wave = t >> 6;
  const int wm = wave >> 1, wn = wave & 1;

  __shared__ __align__(16) u16 Asm[128 * 64];
  __shared__ __align__(16) u16 Bsm[128 * 64];

  const int arq = t & 31, akq = t >> 5;
  int tokr[4];
#pragma unroll
  for (int j = 0; j < 4; ++j) tokr[j] = tok_idx[e * CAP + m0 + arq * 4 + j];
  const int nq = t & 31, kq = t >> 5;
  const float* bptr = w1 + (size_t)e * DIM * HID + n0 + nq * 4;

  f32x4 acc[4][4] = {};

  for (int k0 = 0; k0 < DIM; k0 += 64) {
    float4 av0[4], av1[4];
#pragma unroll
    for (int j = 0; j < 4; ++j) {
      const float* ap = x + (size_t)tokr[j] * DIM + k0 + akq * 8;
      av0[j] = *(const float4*)(ap);
      av1[j] = *(const float4*)(ap + 4);
    }
    float4 bv[8];
#pragma unroll
    for (int kk = 0; kk < 8; ++kk)
      bv[kk] = *(const float4*)(bptr + (size_t)(k0 + kq * 8 + kk) * HID);
    __syncthreads();
#pragma unroll
    for (int j = 0; j < 4; ++j) {
      const int row = arq * 4 + j;
      ushort4 w0, w1v;
      w0.x = f2bf(av0[j].x); w0.y = f2bf(av0[j].y); w0.z = f2bf(av0[j].z); w0.w = f2bf(av0[j].w);
      w1v.x = f2bf(av1[j].x); w1v.y = f2bf(av1[j].y); w1v.z = f2bf(av1[j].z); w1v.w = f2bf(av1[j].w);
      *(ushort4*)((char*)Asm + row * 128 + SWZ(row, (akq * 8 + 0) * 2)) = w0;
      *(ushort4*)((char*)Asm + row * 128 + SWZ(row, (akq * 8 + 4) * 2)) = w1v;
    }
#pragma unroll
    for (int g = 0; g < 2; ++g) {
#pragma unroll
      for (int j = 0; j < 4; ++j) {
        ushort4 wv;
        wv.x = f2bf(GET4(bv[g * 4 + 0], j));
        wv.y = f2bf(GET4(bv[g * 4 + 1], j));
        wv.z = f2bf(GET4(bv[g * 4 + 2], j));
        wv.w = f2bf(GET4(bv[g * 4 + 3], j));
        const int row = nq * 4 + j;
        const int cb = (kq * 8 + g * 4) * 2;
        *(ushort4*)((char*)Bsm + row * 128 + SWZ(row, cb)) = wv;
      }
    }
    __syncthreads();
#pragma unroll
    for (int ks = 0; ks < 2; ++ks) {
      bf16x8 af[4], bf[4];
#pragma unroll
      for (int mi = 0; mi < 4; ++mi) {
        const int row = wm * 64 + mi * 16 + (lane & 15);
        const int cb = ks * 64 + (lane >> 4) * 16;
        af[mi] = *(const bf16x8*)((const char*)Asm + row * 128 + SWZ(row, cb));
      }
#pragma unroll
      for (int ni = 0; ni < 4; ++ni) {
        const int row = wn * 64 + ni * 16 + (lane & 15);
        const int cb = ks * 64 + (lane >> 4) * 16;
        bf[ni] = *(const bf16x8*)((const char*)Bsm + row * 128 + SWZ(row, cb));
      }
#pragma unroll
      for (int mi = 0; mi < 4; ++mi)
#pragma unroll
        for (int ni = 0; ni < 4; ++ni)
          acc[mi][ni] = __builtin_amdgcn_mfma_f32_16x16x32_bf16(af[mi], bf[ni], acc[mi][ni], 0, 0, 0);
    }
  }
  const int lq = lane >> 4, lc = lane & 15;
#pragma unroll
  for (int ni = 0; ni < 4; ++ni) {
    const int n_l = wn * 64 + ni * 16 + lc;
    const float bias = b1[e * HID + n0 + n_l];
#pragma unroll
    for (int mi = 0; mi < 4; ++mi) {
#pragma unroll
      for (int j = 0; j < 4; ++j) {
        const int m_l = wm * 64 + mi * 16 + lq * 4 + j;
        float v = acc[mi][ni][j] + bias;
        float gv = 0.5f * v * (1.0f + erff(v * 0.70710678118654752f));
        h[((size_t)(e * CAP + m0 + m_l)) * HID + (n0 + n_l)] = f2bf(gv);
      }
    }
  }
}

__global__ __launch_bounds__(256)
void fc2_kernel(const u16* __restrict__ h, const float* __restrict__ w2,
                const float* __restrict__ b2, const int* __restrict__ tok_idx,
                const float* __restrict__ expw, float* __restrict__ out) {
  const int bx = blockIdx.x;
  const int e  = bx >> 4;
  const int mt = (bx >> 2) & 3;
  const int nt = bx & 3;
  const int m0 = mt * 128, n0 = nt * 128;
  const int t = threadIdx.x;
  const int lane = t & 63, wave = t >> 6;
  const int wm = wave >> 1, wn = wave & 1;

  __shared__ __align__(16) u16 Asm[128 * 64];
  __shared__ __align__(16) u16 Bsm[128 * 64];

  const int arq = t & 31, akq = t >> 5;
  const u16* aptr0 = h + ((size_t)(e * CAP + m0 + arq * 4)) * HID + akq * 8;
  const int nq = t & 31, kq = t >> 5;
  const float* bptr = w2 + (size_t)e * HID * DIM + n0 + nq * 4;

  f32x4 acc[4][4] = {};

  for (int k0 = 0; k0 < HID; k0 += 64) {
    uint4 av[4];
#pragma unroll
    for (int j = 0; j < 4; ++j)
      av[j] = *(const uint4*)(aptr0 + (size_t)j * HID + k0);
    float4 bv[8];
#pragma unroll
    for (int kk = 0; kk < 8; ++kk)
      bv[kk] = *(const float4*)(bptr + (size_t)(k0 + kq * 8 + kk) * DIM);
    __syncthreads();
#pragma unroll
    for (int j = 0; j < 4; ++j) {
      const int row = arq * 4 + j;
      *(uint4*)((char*)Asm + row * 128 + SWZ(row, akq * 16)) = av[j];
    }
#pragma unroll
    for (int g = 0; g < 2; ++g) {
#pragma unroll
      for (int j = 0; j < 4; ++j) {
        ushort4 wv;
        wv.x = f2bf(GET4(bv[g * 4 + 0], j));
        wv.y = f2bf(GET4(bv[g * 4 + 1], j));
        wv.z = f2bf(GET4(bv[g * 4 + 2], j));
        wv.w = f2bf(GET4(bv[g * 4 + 3], j));
        const int row = nq * 4 + j;
        const int cb = (kq * 8 + g * 4) * 2;
        *(ushort4*)((char*)Bsm + row * 128 + SWZ(row, cb)) = wv;
      }
    }
    __syncthreads();
#pragma unroll
    for (int ks = 0; ks < 2; ++ks) {
      bf16x8 af[4], bf[4];
#pragma unroll
      for (int mi = 0; mi < 4; ++mi) {
        const int row = wm * 64 + mi * 16 + (lane & 15);
        const int cb = ks * 64 + (lane >> 4) * 16;
        af[mi] = *(const bf16x8*)((const char*)Asm + row * 128 + SWZ(row, cb));
      }
#pragma unroll
      for (int ni = 0; ni < 4; ++ni) {
        const int row = wn * 64 + ni * 16 + (lane & 15);
        const int cb = ks * 64 + (lane >> 4) * 16;
        bf[ni] = *(const bf16x8*)((const char*)Bsm + row * 128 + SWZ(row, cb));
      }
#pragma unroll
      for (int mi = 0; mi < 4; ++mi)
#pragma unroll
        for (int ni = 0; ni < 4; ++ni)
          acc[mi][ni] = __builtin_amdgcn_mfma_f32_16x16x32_bf16(af[mi], bf[ni], acc[mi][ni], 0, 0, 0);
    }
  }
  const int lq = lane >> 4, lc = lane & 15;
  int   tokm[4][4];
  float wgt[4][4];
#pragma unroll
  for (int mi = 0; mi < 4; ++mi)
#pragma unroll
    for (int j = 0; j < 4; ++j) {
      const int m_l = wm * 64 + mi * 16 + lq * 4 + j;
      tokm[mi][j] = tok_idx[e * CAP + m0 + m_l];
      wgt[mi][j]  = expw[e * CAP + m0 + m_l];
    }
#pragma unroll
  for (int ni = 0; ni < 4; ++ni) {
    const int n_l = wn * 64 + ni * 16 + lc;
    const float bias = b2[e * DIM + n0 + n_l];
#pragma unroll
    for (int mi = 0; mi < 4; ++mi)
#pragma unroll
      for (int j = 0; j < 4; ++j) {
        float v = (acc[mi][ni][j] + bias) * wgt[mi][j];
        atomicAdd(out + (size_t)tokm[mi][j] * DIM + (n0 + n_l), v);
      }
  }
}

extern "C" void kernel_launch(void* const* d_in, const int* in_sizes, int n_in,
                              void* d_out, int out_size, void* d_ws, size_t ws_size,
                              hipStream_t stream) {
  const float* x  = (const float*)d_in[0];
  const float* rw = (const float*)d_in[1];
  const float* w1 = (const float*)d_in[2];
  const float* b1 = (const float*)d_in[3];
  const float* w2 = (const float*)d_in[4];
  const float* b2 = (const float*)d_in[5];
  float* out = (float*)d_out;

  char* ws = (char*)d_ws;
  const size_t MB = 1u << 20;
  float* logits = (float*)ws;                                   // [0, 8M)
  int*   toki   = (int*)(ws + 8 * MB);                          // 128 KB
  float* ew     = (float*)(ws + 8 * MB + (128u << 10));         // 128 KB

  (void)hipMemsetAsync(d_out, 0, (size_t)out_size * sizeof(float), stream);
  router_kernel<<<dim3(1024), dim3(256), 0, stream>>>(x, rw, logits);
  topk_kernel<<<dim3(64), dim3(1024), 0, stream>>>(logits, toki, ew, out + (size_t)N_TOK * DIM);

  const size_t off_xb = 8 * MB + (256u << 10);   // 8.25M
  const size_t off_wt = off_xb + 32 * MB;        // 40.25M
  const size_t off_h  = off_wt + 64 * MB;        // 104.25M
  const size_t need   = off_h + 64 * MB;         // 168.25M

  if (ws_size >= need) {
    u16* xb  = (u16*)(ws + off_xb);
    u16* wt  = (u16*)(ws + off_wt);
    u16* h   = (u16*)(ws + off_h);
    cvt_bf16_kernel<<<dim3(8192), dim3(256), 0, stream>>>(x, xb);
    transpose_cvt_kernel<<<dim3(16, 8, 64), dim3(256), 0, stream>>>(w1, wt, 512, 1024);
    fc1_bf<<<dim3(2048), dim3(256), 0, stream>>>(xb, toki, wt, b1, h);
    transpose_cvt_kernel<<<dim3(8, 16, 64), dim3(256), 0, stream>>>(w2, wt, 1024, 512);
    fc2_bf<<<dim3(1024), dim3(256), 0, stream>>>(h, wt, b2, toki, ew, out);
  } else {
    u16* h = (u16*)(ws + 8 * MB + (256u << 10)); // old layout
    fc1_kernel<<<dim3(2048), dim3(256), 0, stream>>>(x, toki, w1, b1, h);
    fc2_kernel<<<dim3(1024), dim3(256), 0, stream>>>(h, w2, b2, toki, ew, out);
  }
}